// Round 6
// baseline (1271.668 us; speedup 1.0000x reference)
//
#include <hip/hip_runtime.h>
#include <hip/hip_bf16.h>

#define NN 50000
#define NE 1600000
#define DD 128
#define NB 196   // coarse buckets of 256 nodes: ceil(50000/256)

__device__ __forceinline__ float bf2f(unsigned short u) {
    union { unsigned int i; float f; } c; c.i = ((unsigned int)u) << 16; return c.f;
}
__device__ __forceinline__ unsigned short f2bf(float f) {
    __hip_bfloat16 h = __float2bfloat16(f);
    union { __hip_bfloat16 h; unsigned short u; } c; c.h = h; return c.u;
}
__device__ __forceinline__ int insane_bf16(unsigned short u) {
    unsigned e = (u >> 7) & 0xFF;
    return (e == 0xFF) || (e >= 0x8E);
}

// flags[0]=indices int64; flags[1]=feat f32 (=> out f32); flags[2]=W f32
__global__ void k_detect(const int* __restrict__ srcw, const int* __restrict__ dstw,
                         const unsigned short* __restrict__ feat16,
                         const unsigned short* __restrict__ w16,
                         int* __restrict__ flags) {
    __shared__ int s_idx, s_feat, s_w;
    int tid = threadIdx.x;
    if (tid == 0) { s_idx = 0; s_feat = 0; s_w = 0; }
    __syncthreads();
    if (tid < 64) {
        int v = srcw[2 * tid + 1] | dstw[2 * tid + 1];
        if (v) atomicOr(&s_idx, 1);
    }
    if (insane_bf16(feat16[2 * tid]) || insane_bf16(feat16[2 * tid + 512]))
        atomicOr(&s_feat, 1);
    if (insane_bf16(w16[2 * tid]) || insane_bf16(w16[2 * tid + 512]))
        atomicOr(&s_w, 1);
    __syncthreads();
    if (tid == 0) { flags[0] = (s_idx == 0) ? 1 : 0; flags[1] = s_feat; flags[2] = s_w; }
}

__device__ __forceinline__ int load_idx(const void* p, int e, int is64) {
    long long v = is64 ? ((const long long*)p)[e] : (long long)((const int*)p)[e];
    int i = (int)v;
    return (i < 0) ? 0 : (i >= NN ? NN - 1 : i);
}

__global__ void k_zero(int* __restrict__ deg) {
    int i = blockIdx.x * 256 + threadIdx.x;
    if (i < NN) deg[i] = 0;
}

__global__ void k_degree(const void* __restrict__ dst, int* __restrict__ deg,
                         const int* __restrict__ flags) {
    int e = blockIdx.x * 256 + threadIdx.x;
    if (e >= NE) return;
    atomicAdd(&deg[load_idx(dst, e, flags[0])], 1);
}

// ---- 3-phase scan: per-block sums -> scan of sums -> per-block scan
__global__ __launch_bounds__(256) void k_bsum(const int* __restrict__ deg,
                                              int* __restrict__ bsum) {
    __shared__ int red[256];
    int b = blockIdx.x, tid = threadIdx.x;
    int i = b * 256 + tid;
    red[tid] = (i < NN) ? deg[i] : 0;
    __syncthreads();
    for (int off = 128; off > 0; off >>= 1) {
        if (tid < off) red[tid] += red[tid + off];
        __syncthreads();
    }
    if (tid == 0) bsum[b] = red[0];
}

__global__ __launch_bounds__(256) void k_scanb(const int* __restrict__ bsum,
        int* __restrict__ boff, int* __restrict__ rowptr) {
    __shared__ int buf[256];
    int tid = threadIdx.x;
    int v = (tid < NB) ? bsum[tid] : 0;
    buf[tid] = v;
    __syncthreads();
    for (int off = 1; off < 256; off <<= 1) {
        int t = (tid >= off) ? buf[tid - off] : 0;
        __syncthreads();
        buf[tid] += t;
        __syncthreads();
    }
    if (tid < NB) boff[tid] = buf[tid] - v;
    if (tid == 255) rowptr[NN] = buf[255];
}

__global__ __launch_bounds__(256) void k_scanc(const int* __restrict__ deg,
        const int* __restrict__ boff, int* __restrict__ rowptr,
        int* __restrict__ ccur, float* __restrict__ norm) {
    __shared__ int buf[256];
    int b = blockIdx.x, tid = threadIdx.x;
    int i = b * 256 + tid;
    int v = (i < NN) ? deg[i] : 0;
    buf[tid] = v;
    __syncthreads();
    for (int off = 1; off < 256; off <<= 1) {
        int t = (tid >= off) ? buf[tid - off] : 0;
        __syncthreads();
        buf[tid] += t;
        __syncthreads();
    }
    if (i < NN) {
        rowptr[i] = boff[b] + buf[tid] - v;
        norm[i] = rsqrtf(fmaxf((float)v, 1.0f));
    }
    if (tid == 0) ccur[b] = boff[b];
}

// ---- 2-phase bucketing
// Phase A: stage edges grouped by coarse bucket (quasi-sequential stores)
__global__ void k_bucket2(const void* __restrict__ src, const void* __restrict__ dst,
                          int* __restrict__ ccur, unsigned* __restrict__ staged,
                          const int* __restrict__ flags) {
    int e = blockIdx.x * 256 + threadIdx.x;
    if (e >= NE) return;
    int is64 = flags[0];
    int s = load_idx(src, e, is64);
    int d = load_idx(dst, e, is64);
    int b = d >> 8;
    int pos = atomicAdd(&ccur[b], 1);
    staged[pos] = ((unsigned)(d & 255) << 16) | (unsigned)s;
}

// Phase B: one block per coarse bucket; LDS cursors; writes confined to ~40KB window
__global__ __launch_bounds__(512) void k_bucket3(const unsigned* __restrict__ staged,
        const int* __restrict__ rowptr, int* __restrict__ srclist) {
    __shared__ int curN[256];
    int b = blockIdx.x, tid = threadIdx.x;
    int nbase = b * 256;
    if (tid < 256) {
        int n = nbase + tid;
        curN[tid] = (n < NN) ? rowptr[n] : 0;
    }
    int lo = rowptr[nbase];
    int hiN = nbase + 256; if (hiN > NN) hiN = NN;
    int hi = rowptr[hiN];
    __syncthreads();
    for (int k = lo + tid; k < hi; k += 512) {
        unsigned u = staged[k];
        int nl = u >> 16;
        int pos = atomicAdd(&curN[nl], 1);
        srclist[pos] = (int)(u & 0xffff);
    }
}

// X1[n,d] = feat[n,d] * norm[n]  (bf16), 4 elems/thread
__global__ void k_prescale(const void* __restrict__ feat,
                           const float* __restrict__ norm,
                           unsigned short* __restrict__ X,
                           const int* __restrict__ flags) {
    int i = blockIdx.x * 256 + threadIdx.x;
    if (i >= NN * DD / 4) return;
    float nm = norm[i >> 5];
    float4 v;
    if (flags[1]) {
        v = ((const float4*)feat)[i];
    } else {
        ushort4 f = ((const ushort4*)feat)[i];
        v.x = bf2f(f.x); v.y = bf2f(f.y); v.z = bf2f(f.z); v.w = bf2f(f.w);
    }
    ushort4 o;
    o.x = f2bf(v.x * nm); o.y = f2bf(v.y * nm);
    o.z = f2bf(v.z * nm); o.w = f2bf(v.w * nm);
    ((ushort4*)X)[i] = o;
}

__device__ __forceinline__ void acc8(float* a, uint4 v) {
    a[0] += bf2f((unsigned short)(v.x & 0xffff));
    a[1] += bf2f((unsigned short)(v.x >> 16));
    a[2] += bf2f((unsigned short)(v.y & 0xffff));
    a[3] += bf2f((unsigned short)(v.y >> 16));
    a[4] += bf2f((unsigned short)(v.z & 0xffff));
    a[5] += bf2f((unsigned short)(v.z >> 16));
    a[6] += bf2f((unsigned short)(v.w & 0xffff));
    a[7] += bf2f((unsigned short)(v.w >> 16));
}

// gather-reduce: one wave per dst node; 4 edge-slots x 16 lanes x 16B rows.
// mode 0: out = bf16(acc * norm[n]^2) -> X2;  mode 1: out = acc (f32/bf16) -> d_out
__global__ __launch_bounds__(256) void k_gather(const unsigned short* __restrict__ Xin,
        const int* __restrict__ rowptr, const int* __restrict__ srclist,
        const float* __restrict__ norm, void* __restrict__ outp,
        const int* __restrict__ flags, int mode) {
    int wid = (blockIdx.x * 256 + threadIdx.x) >> 6;
    int lane = threadIdx.x & 63;
    if (wid >= NN) return;
    int beg = rowptr[wid], end = rowptr[wid + 1];
    int g = lane >> 4;
    int c8 = (lane & 15) << 3;
    const unsigned short* xb = Xin + c8;
    float a[8];
    #pragma unroll
    for (int k = 0; k < 8; ++k) a[k] = 0.f;

    for (int j = beg + g; j < end; j += 8) {
        int s0 = srclist[j];
        uint4 v0 = *(const uint4*)(xb + s0 * DD);
        int j2 = j + 4;
        if (j2 < end) {
            int s1 = srclist[j2];
            uint4 v1 = *(const uint4*)(xb + s1 * DD);
            acc8(a, v0);
            acc8(a, v1);
        } else {
            acc8(a, v0);
        }
    }
    #pragma unroll
    for (int k = 0; k < 8; ++k) {
        a[k] += __shfl_xor(a[k], 16);
        a[k] += __shfl_xor(a[k], 32);
    }

    if (mode == 0) {
        if (g == 0) {
            float nm = norm[wid]; float n2 = nm * nm;
            uint4 o;
            o.x = ((unsigned)f2bf(a[1] * n2) << 16) | (unsigned)f2bf(a[0] * n2);
            o.y = ((unsigned)f2bf(a[3] * n2) << 16) | (unsigned)f2bf(a[2] * n2);
            o.z = ((unsigned)f2bf(a[5] * n2) << 16) | (unsigned)f2bf(a[4] * n2);
            o.w = ((unsigned)f2bf(a[7] * n2) << 16) | (unsigned)f2bf(a[6] * n2);
            *(uint4*)((unsigned short*)outp + wid * DD + c8) = o;
        }
    } else if (flags[1]) {
        if (g == 0)
            *(float4*)((float*)outp + wid * DD + c8) = make_float4(a[0], a[1], a[2], a[3]);
        else if (g == 1)
            *(float4*)((float*)outp + wid * DD + c8 + 4) = make_float4(a[4], a[5], a[6], a[7]);
    } else {
        if (g == 0) {
            uint4 o;
            o.x = ((unsigned)f2bf(a[1]) << 16) | (unsigned)f2bf(a[0]);
            o.y = ((unsigned)f2bf(a[3]) << 16) | (unsigned)f2bf(a[2]);
            o.z = ((unsigned)f2bf(a[5]) << 16) | (unsigned)f2bf(a[4]);
            o.w = ((unsigned)f2bf(a[7]) << 16) | (unsigned)f2bf(a[6]);
            *(uint4*)((unsigned short*)outp + wid * DD + c8) = o;
        }
    }
}

// In-place GEMM on d_out: out[n,:] = (Y[n,:]*norm[n]) @ W^T + b
__global__ __launch_bounds__(256) void k_gemm(void* __restrict__ Yio,
        const float* __restrict__ norm, const void* __restrict__ Wp,
        const void* __restrict__ bp, const int* __restrict__ flags) {
    __shared__ unsigned int uw[DD * 65];
    __shared__ float Fl[32 * 130];
    int tid = threadIdx.x;
    int nodeBase = blockIdx.x * 32;
    int wf32 = flags[2];
    int of32 = flags[1];

    for (int idx = tid; idx < DD * 64; idx += 256) {
        int o = idx >> 6, kk = idx & 63;
        unsigned pk;
        if (wf32) {
            float2 w = ((const float2*)Wp)[o * 64 + kk];
            pk = ((unsigned)f2bf(w.y) << 16) | (unsigned)f2bf(w.x);
        } else {
            pk = ((const unsigned*)Wp)[o * 64 + kk];
        }
        uw[o * 65 + kk] = pk;
    }
    for (int idx = tid; idx < 32 * DD; idx += 256) {
        int nl = idx >> 7, d = idx & 127;
        int n = nodeBase + nl;
        float v = 0.0f;
        if (n < NN) {
            float nm = norm[n];
            v = of32 ? ((const float*)Yio)[n * DD + d] * nm
                     : bf2f(((const unsigned short*)Yio)[n * DD + d]) * nm;
        }
        Fl[nl * 130 + d] = v;
    }
    __syncthreads();

    int og = tid & 15;
    int ng = tid >> 4;
    int nl0 = ng * 2;
    float acc0[8], acc1[8];
    #pragma unroll
    for (int j = 0; j < 8; ++j) { acc0[j] = 0.f; acc1[j] = 0.f; }
    const float* r0 = &Fl[nl0 * 130];
    const float* r1 = &Fl[(nl0 + 1) * 130];
    #pragma unroll 4
    for (int kk = 0; kk < 64; ++kk) {
        float2 f0 = *(const float2*)(r0 + 2 * kk);
        float2 f1 = *(const float2*)(r1 + 2 * kk);
        #pragma unroll
        for (int j = 0; j < 8; ++j) {
            unsigned w = uw[(og + 16 * j) * 65 + kk];
            float w0 = bf2f((unsigned short)(w & 0xffff));
            float w1 = bf2f((unsigned short)(w >> 16));
            acc0[j] += f0.x * w0 + f0.y * w1;
            acc1[j] += f1.x * w0 + f1.y * w1;
        }
    }
    int n0 = nodeBase + nl0;
    #pragma unroll
    for (int j = 0; j < 8; ++j) {
        int o = og + 16 * j;
        float bias = wf32 ? ((const float*)bp)[o] : bf2f(((const unsigned short*)bp)[o]);
        float v0 = acc0[j] + bias, v1 = acc1[j] + bias;
        if (of32) {
            float* out = (float*)Yio;
            if (n0 < NN)     out[n0 * DD + o] = v0;
            if (n0 + 1 < NN) out[(n0 + 1) * DD + o] = v1;
        } else {
            unsigned short* out = (unsigned short*)Yio;
            if (n0 < NN)     out[n0 * DD + o] = f2bf(v0);
            if (n0 + 1 < NN) out[(n0 + 1) * DD + o] = f2bf(v1);
        }
    }
}

extern "C" void kernel_launch(void* const* d_in, const int* in_sizes, int n_in,
                              void* d_out, int out_size, void* d_ws, size_t ws_size,
                              hipStream_t stream) {
    const void* feat = d_in[0];
    const void* src  = d_in[1];
    const void* dst  = d_in[2];
    const void* W    = d_in[3];
    const void* b    = d_in[4];

    // ws (bytes): flags@0 | deg@32 | rowptr@200032 | bsum@400064 | boff@400896 |
    //   ccur@401728 | norm@402560 | srclist@602624 | X1@7002624 | X2@19802624
    //   (staged aliases X2's first 6.4MB; X2 written only after staged is dead)
    char* wsb = (char*)d_ws;
    int*   flags   = (int*)wsb;
    int*   deg     = (int*)(wsb + 32);
    int*   rowptr  = (int*)(wsb + 200032);
    int*   bsum    = (int*)(wsb + 400064);
    int*   boff    = (int*)(wsb + 400896);
    int*   ccur    = (int*)(wsb + 401728);
    float* norm    = (float*)(wsb + 402560);
    int*   srclist = (int*)(wsb + 602624);
    unsigned short* X1 = (unsigned short*)(wsb + 7002624);
    unsigned short* X2 = (unsigned short*)(wsb + 19802624);
    unsigned* staged   = (unsigned*)(wsb + 19802624);

    k_detect<<<1, 256, 0, stream>>>((const int*)src, (const int*)dst,
                                    (const unsigned short*)feat,
                                    (const unsigned short*)W, flags);
    k_zero<<<(NN + 255) / 256, 256, 0, stream>>>(deg);
    k_degree<<<(NE + 255) / 256, 256, 0, stream>>>(dst, deg, flags);
    k_bsum<<<NB, 256, 0, stream>>>(deg, bsum);
    k_scanb<<<1, 256, 0, stream>>>(bsum, boff, rowptr);
    k_scanc<<<NB, 256, 0, stream>>>(deg, boff, rowptr, ccur, norm);
    k_bucket2<<<(NE + 255) / 256, 256, 0, stream>>>(src, dst, ccur, staged, flags);
    k_bucket3<<<NB, 512, 0, stream>>>(staged, rowptr, srclist);
    k_prescale<<<(NN * DD / 4 + 255) / 256, 256, 0, stream>>>(feat, norm, X1, flags);
    k_gather<<<(NN + 3) / 4, 256, 0, stream>>>(X1, rowptr, srclist, norm, X2, flags, 0);
    k_gather<<<(NN + 3) / 4, 256, 0, stream>>>(X2, rowptr, srclist, norm, d_out, flags, 1);
    k_gemm<<<(NN + 31) / 32, 256, 0, stream>>>(d_out, norm, W, b, flags);
}

// Round 7
// 452.800 us; speedup vs baseline: 2.8085x; 2.8085x over previous
//
#include <hip/hip_runtime.h>
#include <hip/hip_bf16.h>

#define NN 50000
#define NE 1600000
#define DD 128
#define NB 196        // scan blocks of 256 nodes: ceil(50000/256)
#define SLICE 6250    // nodes per XCD team (8 teams)

__device__ __forceinline__ float bf2f(unsigned short u) {
    union { unsigned int i; float f; } c; c.i = ((unsigned int)u) << 16; return c.f;
}
__device__ __forceinline__ unsigned short f2bf(float f) {
    __hip_bfloat16 h = __float2bfloat16(f);
    union { __hip_bfloat16 h; unsigned short u; } c; c.h = h; return c.u;
}
__device__ __forceinline__ int insane_bf16(unsigned short u) {
    unsigned e = (u >> 7) & 0xFF;
    return (e == 0xFF) || (e >= 0x8E);
}

// flags[0]=indices int64; flags[1]=feat f32 (=> out f32); flags[2]=W f32
__global__ void k_detect(const int* __restrict__ srcw, const int* __restrict__ dstw,
                         const unsigned short* __restrict__ feat16,
                         const unsigned short* __restrict__ w16,
                         int* __restrict__ flags) {
    __shared__ int s_idx, s_feat, s_w;
    int tid = threadIdx.x;
    if (tid == 0) { s_idx = 0; s_feat = 0; s_w = 0; }
    __syncthreads();
    if (tid < 64) {
        int v = srcw[2 * tid + 1] | dstw[2 * tid + 1];
        if (v) atomicOr(&s_idx, 1);
    }
    if (insane_bf16(feat16[2 * tid]) || insane_bf16(feat16[2 * tid + 512]))
        atomicOr(&s_feat, 1);
    if (insane_bf16(w16[2 * tid]) || insane_bf16(w16[2 * tid + 512]))
        atomicOr(&s_w, 1);
    __syncthreads();
    if (tid == 0) { flags[0] = (s_idx == 0) ? 1 : 0; flags[1] = s_feat; flags[2] = s_w; }
}

__device__ __forceinline__ int load_idx(const void* p, int e, int is64) {
    long long v = is64 ? ((const long long*)p)[e] : (long long)((const int*)p)[e];
    int i = (int)v;
    return (i < 0) ? 0 : (i >= NN ? NN - 1 : i);
}

__global__ void k_zero(int* __restrict__ deg) {
    int i = blockIdx.x * 256 + threadIdx.x;
    if (i < NN) deg[i] = 0;
}

__global__ void k_degree(const void* __restrict__ dst, int* __restrict__ deg,
                         const int* __restrict__ flags) {
    int e = blockIdx.x * 256 + threadIdx.x;
    if (e >= NE) return;
    atomicAdd(&deg[load_idx(dst, e, flags[0])], 1);
}

// ---- 3-phase scan: per-block sums -> scan of sums -> per-block scan
__global__ __launch_bounds__(256) void k_bsum(const int* __restrict__ deg,
                                              int* __restrict__ bsum) {
    __shared__ int red[256];
    int b = blockIdx.x, tid = threadIdx.x;
    int i = b * 256 + tid;
    red[tid] = (i < NN) ? deg[i] : 0;
    __syncthreads();
    for (int off = 128; off > 0; off >>= 1) {
        if (tid < off) red[tid] += red[tid + off];
        __syncthreads();
    }
    if (tid == 0) bsum[b] = red[0];
}

__global__ __launch_bounds__(256) void k_scanb(const int* __restrict__ bsum,
        int* __restrict__ boff, int* __restrict__ rowptr) {
    __shared__ int buf[256];
    int tid = threadIdx.x;
    int v = (tid < NB) ? bsum[tid] : 0;
    buf[tid] = v;
    __syncthreads();
    for (int off = 1; off < 256; off <<= 1) {
        int t = (tid >= off) ? buf[tid - off] : 0;
        __syncthreads();
        buf[tid] += t;
        __syncthreads();
    }
    if (tid < NB) boff[tid] = buf[tid] - v;
    if (tid == 255) rowptr[NN] = buf[255];
}

// writes rowptr, full cursor copy, norm
__global__ __launch_bounds__(256) void k_scanc(const int* __restrict__ deg,
        const int* __restrict__ boff, int* __restrict__ rowptr,
        int* __restrict__ cur, float* __restrict__ norm) {
    __shared__ int buf[256];
    int b = blockIdx.x, tid = threadIdx.x;
    int i = b * 256 + tid;
    int v = (i < NN) ? deg[i] : 0;
    buf[tid] = v;
    __syncthreads();
    for (int off = 1; off < 256; off <<= 1) {
        int t = (tid >= off) ? buf[tid - off] : 0;
        __syncthreads();
        buf[tid] += t;
        __syncthreads();
    }
    if (i < NN) {
        int rp = boff[b] + buf[tid] - v;
        rowptr[i] = rp;
        cur[i] = rp;
        norm[i] = rsqrtf(fmaxf((float)v, 1.0f));
    }
}

// XCD-sliced CSR fill: team = blockIdx&7 commits only dst in its slice, so each
// XCD's L2 holds only its 0.8MB srclist slice + its cursor slice (no cross-XCD
// line duplication -> one writeback per line instead of ~16).
__global__ __launch_bounds__(256) void k_bucketx(const void* __restrict__ src,
        const void* __restrict__ dst, int* __restrict__ cur,
        int* __restrict__ srclist, const int* __restrict__ flags) {
    int team = blockIdx.x & 7;
    int chunk = blockIdx.x >> 3;           // 0..255
    const int per = (NE + 255) / 256;      // 6250 edges per chunk
    int lo = chunk * per;
    int hi = lo + per; if (hi > NE) hi = NE;
    int is64 = flags[0];
    for (int e = lo + threadIdx.x; e < hi; e += 256) {
        int d = load_idx(dst, e, is64);
        if (d / SLICE == team) {
            int s = load_idx(src, e, is64);
            int pos = atomicAdd(&cur[d], 1);
            srclist[pos] = s;
        }
    }
}

// X1[n,d] = feat[n,d] * norm[n]  (bf16), 4 elems/thread
__global__ void k_prescale(const void* __restrict__ feat,
                           const float* __restrict__ norm,
                           unsigned short* __restrict__ X,
                           const int* __restrict__ flags) {
    int i = blockIdx.x * 256 + threadIdx.x;
    if (i >= NN * DD / 4) return;
    float nm = norm[i >> 5];
    float4 v;
    if (flags[1]) {
        v = ((const float4*)feat)[i];
    } else {
        ushort4 f = ((const ushort4*)feat)[i];
        v.x = bf2f(f.x); v.y = bf2f(f.y); v.z = bf2f(f.z); v.w = bf2f(f.w);
    }
    ushort4 o;
    o.x = f2bf(v.x * nm); o.y = f2bf(v.y * nm);
    o.z = f2bf(v.z * nm); o.w = f2bf(v.w * nm);
    ((ushort4*)X)[i] = o;
}

__device__ __forceinline__ void acc8(float* a, uint4 v) {
    a[0] += bf2f((unsigned short)(v.x & 0xffff));
    a[1] += bf2f((unsigned short)(v.x >> 16));
    a[2] += bf2f((unsigned short)(v.y & 0xffff));
    a[3] += bf2f((unsigned short)(v.y >> 16));
    a[4] += bf2f((unsigned short)(v.z & 0xffff));
    a[5] += bf2f((unsigned short)(v.z >> 16));
    a[6] += bf2f((unsigned short)(v.w & 0xffff));
    a[7] += bf2f((unsigned short)(v.w >> 16));
}

// gather-reduce: one wave per dst node; 4 edge-slots x 16 lanes x 16B rows.
// mode 0: out = bf16(acc * norm[n]^2) -> X2;  mode 1: out = acc (f32/bf16) -> d_out
__global__ __launch_bounds__(256) void k_gather(const unsigned short* __restrict__ Xin,
        const int* __restrict__ rowptr, const int* __restrict__ srclist,
        const float* __restrict__ norm, void* __restrict__ outp,
        const int* __restrict__ flags, int mode) {
    int wid = (blockIdx.x * 256 + threadIdx.x) >> 6;
    int lane = threadIdx.x & 63;
    if (wid >= NN) return;
    int beg = rowptr[wid], end = rowptr[wid + 1];
    int g = lane >> 4;
    int c8 = (lane & 15) << 3;
    const unsigned short* xb = Xin + c8;
    float a[8];
    #pragma unroll
    for (int k = 0; k < 8; ++k) a[k] = 0.f;

    for (int j = beg + g; j < end; j += 8) {
        int s0 = srclist[j];
        uint4 v0 = *(const uint4*)(xb + s0 * DD);
        int j2 = j + 4;
        if (j2 < end) {
            int s1 = srclist[j2];
            uint4 v1 = *(const uint4*)(xb + s1 * DD);
            acc8(a, v0);
            acc8(a, v1);
        } else {
            acc8(a, v0);
        }
    }
    #pragma unroll
    for (int k = 0; k < 8; ++k) {
        a[k] += __shfl_xor(a[k], 16);
        a[k] += __shfl_xor(a[k], 32);
    }

    if (mode == 0) {
        if (g == 0) {
            float nm = norm[wid]; float n2 = nm * nm;
            uint4 o;
            o.x = ((unsigned)f2bf(a[1] * n2) << 16) | (unsigned)f2bf(a[0] * n2);
            o.y = ((unsigned)f2bf(a[3] * n2) << 16) | (unsigned)f2bf(a[2] * n2);
            o.z = ((unsigned)f2bf(a[5] * n2) << 16) | (unsigned)f2bf(a[4] * n2);
            o.w = ((unsigned)f2bf(a[7] * n2) << 16) | (unsigned)f2bf(a[6] * n2);
            *(uint4*)((unsigned short*)outp + wid * DD + c8) = o;
        }
    } else if (flags[1]) {
        if (g == 0)
            *(float4*)((float*)outp + wid * DD + c8) = make_float4(a[0], a[1], a[2], a[3]);
        else if (g == 1)
            *(float4*)((float*)outp + wid * DD + c8 + 4) = make_float4(a[4], a[5], a[6], a[7]);
    } else {
        if (g == 0) {
            uint4 o;
            o.x = ((unsigned)f2bf(a[1]) << 16) | (unsigned)f2bf(a[0]);
            o.y = ((unsigned)f2bf(a[3]) << 16) | (unsigned)f2bf(a[2]);
            o.z = ((unsigned)f2bf(a[5]) << 16) | (unsigned)f2bf(a[4]);
            o.w = ((unsigned)f2bf(a[7]) << 16) | (unsigned)f2bf(a[6]);
            *(uint4*)((unsigned short*)outp + wid * DD + c8) = o;
        }
    }
}

// In-place GEMM on d_out: out[n,:] = (Y[n,:]*norm[n]) @ W^T + b
__global__ __launch_bounds__(256) void k_gemm(void* __restrict__ Yio,
        const float* __restrict__ norm, const void* __restrict__ Wp,
        const void* __restrict__ bp, const int* __restrict__ flags) {
    __shared__ unsigned int uw[DD * 65];
    __shared__ float Fl[32 * 130];
    int tid = threadIdx.x;
    int nodeBase = blockIdx.x * 32;
    int wf32 = flags[2];
    int of32 = flags[1];

    for (int idx = tid; idx < DD * 64; idx += 256) {
        int o = idx >> 6, kk = idx & 63;
        unsigned pk;
        if (wf32) {
            float2 w = ((const float2*)Wp)[o * 64 + kk];
            pk = ((unsigned)f2bf(w.y) << 16) | (unsigned)f2bf(w.x);
        } else {
            pk = ((const unsigned*)Wp)[o * 64 + kk];
        }
        uw[o * 65 + kk] = pk;
    }
    for (int idx = tid; idx < 32 * DD; idx += 256) {
        int nl = idx >> 7, d = idx & 127;
        int n = nodeBase + nl;
        float v = 0.0f;
        if (n < NN) {
            float nm = norm[n];
            v = of32 ? ((const float*)Yio)[n * DD + d] * nm
                     : bf2f(((const unsigned short*)Yio)[n * DD + d]) * nm;
        }
        Fl[nl * 130 + d] = v;
    }
    __syncthreads();

    int og = tid & 15;
    int ng = tid >> 4;
    int nl0 = ng * 2;
    float acc0[8], acc1[8];
    #pragma unroll
    for (int j = 0; j < 8; ++j) { acc0[j] = 0.f; acc1[j] = 0.f; }
    const float* r0 = &Fl[nl0 * 130];
    const float* r1 = &Fl[(nl0 + 1) * 130];
    #pragma unroll 4
    for (int kk = 0; kk < 64; ++kk) {
        float2 f0 = *(const float2*)(r0 + 2 * kk);
        float2 f1 = *(const float2*)(r1 + 2 * kk);
        #pragma unroll
        for (int j = 0; j < 8; ++j) {
            unsigned w = uw[(og + 16 * j) * 65 + kk];
            float w0 = bf2f((unsigned short)(w & 0xffff));
            float w1 = bf2f((unsigned short)(w >> 16));
            acc0[j] += f0.x * w0 + f0.y * w1;
            acc1[j] += f1.x * w0 + f1.y * w1;
        }
    }
    int n0 = nodeBase + nl0;
    #pragma unroll
    for (int j = 0; j < 8; ++j) {
        int o = og + 16 * j;
        float bias = wf32 ? ((const float*)bp)[o] : bf2f(((const unsigned short*)bp)[o]);
        float v0 = acc0[j] + bias, v1 = acc1[j] + bias;
        if (of32) {
            float* out = (float*)Yio;
            if (n0 < NN)     out[n0 * DD + o] = v0;
            if (n0 + 1 < NN) out[(n0 + 1) * DD + o] = v1;
        } else {
            unsigned short* out = (unsigned short*)Yio;
            if (n0 < NN)     out[n0 * DD + o] = f2bf(v0);
            if (n0 + 1 < NN) out[(n0 + 1) * DD + o] = f2bf(v1);
        }
    }
}

extern "C" void kernel_launch(void* const* d_in, const int* in_sizes, int n_in,
                              void* d_out, int out_size, void* d_ws, size_t ws_size,
                              hipStream_t stream) {
    const void* feat = d_in[0];
    const void* src  = d_in[1];
    const void* dst  = d_in[2];
    const void* W    = d_in[3];
    const void* b    = d_in[4];

    // ws (bytes): flags@0 | deg@32 | rowptr@200032 | cur@400064 | norm@600064 |
    //   srclist@800064 | X1@7200064 | X2@20000064 | bsum@32800064 | boff@32800864
    char* wsb = (char*)d_ws;
    int*   flags   = (int*)wsb;
    int*   deg     = (int*)(wsb + 32);
    int*   rowptr  = (int*)(wsb + 200032);
    int*   cur     = (int*)(wsb + 400064);
    float* norm    = (float*)(wsb + 600064);
    int*   srclist = (int*)(wsb + 800064);
    unsigned short* X1 = (unsigned short*)(wsb + 7200064);
    unsigned short* X2 = (unsigned short*)(wsb + 20000064);
    int*   bsum    = (int*)(wsb + 32800064);
    int*   boff    = (int*)(wsb + 32800864);

    k_detect<<<1, 256, 0, stream>>>((const int*)src, (const int*)dst,
                                    (const unsigned short*)feat,
                                    (const unsigned short*)W, flags);
    k_zero<<<(NN + 255) / 256, 256, 0, stream>>>(deg);
    k_degree<<<(NE + 255) / 256, 256, 0, stream>>>(dst, deg, flags);
    k_bsum<<<NB, 256, 0, stream>>>(deg, bsum);
    k_scanb<<<1, 256, 0, stream>>>(bsum, boff, rowptr);
    k_scanc<<<NB, 256, 0, stream>>>(deg, boff, rowptr, cur, norm);
    k_bucketx<<<2048, 256, 0, stream>>>(src, dst, cur, srclist, flags);
    k_prescale<<<(NN * DD / 4 + 255) / 256, 256, 0, stream>>>(feat, norm, X1, flags);
    k_gather<<<(NN + 3) / 4, 256, 0, stream>>>(X1, rowptr, srclist, norm, X2, flags, 0);
    k_gather<<<(NN + 3) / 4, 256, 0, stream>>>(X2, rowptr, srclist, norm, d_out, flags, 1);
    k_gemm<<<(NN + 31) / 32, 256, 0, stream>>>(d_out, norm, W, b, flags);
}

// Round 8
// 397.746 us; speedup vs baseline: 3.1972x; 1.1384x over previous
//
#include <hip/hip_runtime.h>
#include <hip/hip_bf16.h>

#define NN 50000
#define NE 1600000
#define DD 128
#define NB 196        // scan blocks of 256 nodes: ceil(50000/256)
#define SLICE 6250    // nodes per XCD team (8 teams)

typedef short bfrag __attribute__((ext_vector_type(8)));   // 8 bf16 = 4 VGPR
typedef float ffrag __attribute__((ext_vector_type(4)));   // 4 f32 acc

__device__ __forceinline__ float bf2f(unsigned short u) {
    union { unsigned int i; float f; } c; c.i = ((unsigned int)u) << 16; return c.f;
}
__device__ __forceinline__ unsigned short f2bf(float f) {
    __hip_bfloat16 h = __float2bfloat16(f);
    union { __hip_bfloat16 h; unsigned short u; } c; c.h = h; return c.u;
}
__device__ __forceinline__ int insane_bf16(unsigned short u) {
    unsigned e = (u >> 7) & 0xFF;
    return (e == 0xFF) || (e >= 0x8E);
}

// flags[0]=indices int64; flags[1]=feat f32 (=> out f32); flags[2]=W f32
__global__ void k_detect(const int* __restrict__ srcw, const int* __restrict__ dstw,
                         const unsigned short* __restrict__ feat16,
                         const unsigned short* __restrict__ w16,
                         int* __restrict__ flags) {
    __shared__ int s_idx, s_feat, s_w;
    int tid = threadIdx.x;
    if (tid == 0) { s_idx = 0; s_feat = 0; s_w = 0; }
    __syncthreads();
    if (tid < 64) {
        int v = srcw[2 * tid + 1] | dstw[2 * tid + 1];
        if (v) atomicOr(&s_idx, 1);
    }
    if (insane_bf16(feat16[2 * tid]) || insane_bf16(feat16[2 * tid + 512]))
        atomicOr(&s_feat, 1);
    if (insane_bf16(w16[2 * tid]) || insane_bf16(w16[2 * tid + 512]))
        atomicOr(&s_w, 1);
    __syncthreads();
    if (tid == 0) { flags[0] = (s_idx == 0) ? 1 : 0; flags[1] = s_feat; flags[2] = s_w; }
}

__device__ __forceinline__ int load_idx(const void* p, int e, int is64) {
    long long v = is64 ? ((const long long*)p)[e] : (long long)((const int*)p)[e];
    int i = (int)v;
    return (i < 0) ? 0 : (i >= NN ? NN - 1 : i);
}

__global__ void k_zero(int* __restrict__ deg) {
    int i = blockIdx.x * 256 + threadIdx.x;
    if (i < NN) deg[i] = 0;
}

__global__ void k_degree(const void* __restrict__ dst, int* __restrict__ deg,
                         const int* __restrict__ flags) {
    int e = blockIdx.x * 256 + threadIdx.x;
    if (e >= NE) return;
    atomicAdd(&deg[load_idx(dst, e, flags[0])], 1);
}

// ---- 3-phase scan
__global__ __launch_bounds__(256) void k_bsum(const int* __restrict__ deg,
                                              int* __restrict__ bsum) {
    __shared__ int red[256];
    int b = blockIdx.x, tid = threadIdx.x;
    int i = b * 256 + tid;
    red[tid] = (i < NN) ? deg[i] : 0;
    __syncthreads();
    for (int off = 128; off > 0; off >>= 1) {
        if (tid < off) red[tid] += red[tid + off];
        __syncthreads();
    }
    if (tid == 0) bsum[b] = red[0];
}

__global__ __launch_bounds__(256) void k_scanb(const int* __restrict__ bsum,
        int* __restrict__ boff, int* __restrict__ rowptr) {
    __shared__ int buf[256];
    int tid = threadIdx.x;
    int v = (tid < NB) ? bsum[tid] : 0;
    buf[tid] = v;
    __syncthreads();
    for (int off = 1; off < 256; off <<= 1) {
        int t = (tid >= off) ? buf[tid - off] : 0;
        __syncthreads();
        buf[tid] += t;
        __syncthreads();
    }
    if (tid < NB) boff[tid] = buf[tid] - v;
    if (tid == 255) rowptr[NN] = buf[255];
}

__global__ __launch_bounds__(256) void k_scanc(const int* __restrict__ deg,
        const int* __restrict__ boff, int* __restrict__ rowptr,
        int* __restrict__ cur, float* __restrict__ norm) {
    __shared__ int buf[256];
    int b = blockIdx.x, tid = threadIdx.x;
    int i = b * 256 + tid;
    int v = (i < NN) ? deg[i] : 0;
    buf[tid] = v;
    __syncthreads();
    for (int off = 1; off < 256; off <<= 1) {
        int t = (tid >= off) ? buf[tid - off] : 0;
        __syncthreads();
        buf[tid] += t;
        __syncthreads();
    }
    if (i < NN) {
        int rp = boff[b] + buf[tid] - v;
        rowptr[i] = rp;
        cur[i] = rp;
        norm[i] = rsqrtf(fmaxf((float)v, 1.0f));
    }
}

// XCD-sliced CSR fill
__global__ __launch_bounds__(256) void k_bucketx(const void* __restrict__ src,
        const void* __restrict__ dst, int* __restrict__ cur,
        int* __restrict__ srclist, const int* __restrict__ flags) {
    int team = blockIdx.x & 7;
    int chunk = blockIdx.x >> 3;
    const int per = (NE + 255) / 256;
    int lo = chunk * per;
    int hi = lo + per; if (hi > NE) hi = NE;
    int is64 = flags[0];
    for (int e = lo + threadIdx.x; e < hi; e += 256) {
        int d = load_idx(dst, e, is64);
        if (d / SLICE == team) {
            int s = load_idx(src, e, is64);
            int pos = atomicAdd(&cur[d], 1);
            srclist[pos] = s;
        }
    }
}

// X1[n,d] = feat[n,d] * norm[n]  (bf16)
__global__ void k_prescale(const void* __restrict__ feat,
                           const float* __restrict__ norm,
                           unsigned short* __restrict__ X,
                           const int* __restrict__ flags) {
    int i = blockIdx.x * 256 + threadIdx.x;
    if (i >= NN * DD / 4) return;
    float nm = norm[i >> 5];
    float4 v;
    if (flags[1]) {
        v = ((const float4*)feat)[i];
    } else {
        ushort4 f = ((const ushort4*)feat)[i];
        v.x = bf2f(f.x); v.y = bf2f(f.y); v.z = bf2f(f.z); v.w = bf2f(f.w);
    }
    ushort4 o;
    o.x = f2bf(v.x * nm); o.y = f2bf(v.y * nm);
    o.z = f2bf(v.z * nm); o.w = f2bf(v.w * nm);
    ((ushort4*)X)[i] = o;
}

__device__ __forceinline__ void acc8(float* a, uint4 v) {
    a[0] += bf2f((unsigned short)(v.x & 0xffff));
    a[1] += bf2f((unsigned short)(v.x >> 16));
    a[2] += bf2f((unsigned short)(v.y & 0xffff));
    a[3] += bf2f((unsigned short)(v.y >> 16));
    a[4] += bf2f((unsigned short)(v.z & 0xffff));
    a[5] += bf2f((unsigned short)(v.z >> 16));
    a[6] += bf2f((unsigned short)(v.w & 0xffff));
    a[7] += bf2f((unsigned short)(v.w >> 16));
}

// gather-reduce: one wave per dst node; 4 edge-slots x 16 lanes x 16B rows.
// mode 0: out = bf16(acc * norm^2) -> X2   (hop1 post-norm x hop2 pre-norm)
// mode 1: out = bf16(acc * norm)   -> Yb   (hop2 post-norm; GEMM A operand)
__global__ __launch_bounds__(256) void k_gather(const unsigned short* __restrict__ Xin,
        const int* __restrict__ rowptr, const int* __restrict__ srclist,
        const float* __restrict__ norm, unsigned short* __restrict__ outp,
        int mode) {
    int wid = (blockIdx.x * 256 + threadIdx.x) >> 6;
    int lane = threadIdx.x & 63;
    if (wid >= NN) return;
    int beg = rowptr[wid], end = rowptr[wid + 1];
    int g = lane >> 4;
    int c8 = (lane & 15) << 3;
    const unsigned short* xb = Xin + c8;
    float a[8];
    #pragma unroll
    for (int k = 0; k < 8; ++k) a[k] = 0.f;

    for (int j = beg + g; j < end; j += 8) {
        int s0 = srclist[j];
        uint4 v0 = *(const uint4*)(xb + s0 * DD);
        int j2 = j + 4;
        if (j2 < end) {
            int s1 = srclist[j2];
            uint4 v1 = *(const uint4*)(xb + s1 * DD);
            acc8(a, v0);
            acc8(a, v1);
        } else {
            acc8(a, v0);
        }
    }
    #pragma unroll
    for (int k = 0; k < 8; ++k) {
        a[k] += __shfl_xor(a[k], 16);
        a[k] += __shfl_xor(a[k], 32);
    }

    if (g == 0) {
        float nm = norm[wid];
        float sc = (mode == 0) ? nm * nm : nm;
        uint4 o;
        o.x = ((unsigned)f2bf(a[1] * sc) << 16) | (unsigned)f2bf(a[0] * sc);
        o.y = ((unsigned)f2bf(a[3] * sc) << 16) | (unsigned)f2bf(a[2] * sc);
        o.z = ((unsigned)f2bf(a[5] * sc) << 16) | (unsigned)f2bf(a[4] * sc);
        o.w = ((unsigned)f2bf(a[7] * sc) << 16) | (unsigned)f2bf(a[6] * sc);
        *(uint4*)(outp + wid * DD + c8) = o;
    }
}

// MFMA GEMM: out[n,o] = Yb[n,:] @ W[o,:] + b[o].  Yb is bf16 (norm applied).
// 256 thr = 4 waves = 64 nodes/block. W in LDS bf16, row stride 136 (2-way max).
// Frag layouts (guide §3, m89-verified): A[m=lane&15][k=quad*8+j],
// B[n=lane&15][k=quad*8+j], D col=lane&15, row=quad*4+reg.
__global__ __launch_bounds__(256) void k_gemm2(const unsigned short* __restrict__ Yb,
        const void* __restrict__ Wp, const void* __restrict__ bp,
        void* __restrict__ outp, const int* __restrict__ flags) {
    __shared__ unsigned short Wl[DD * 136];   // 34,816 B
    int tid = threadIdx.x;
    int wf32 = flags[2], of32 = flags[1];

    // stage W (bf16-packed), 8192 dwords
    for (int i = tid; i < 8192; i += 256) {
        int r = i >> 6, cc = i & 63;
        unsigned pk;
        if (wf32) {
            float2 w = ((const float2*)Wp)[i];
            pk = ((unsigned)f2bf(w.y) << 16) | (unsigned)f2bf(w.x);
        } else {
            pk = ((const unsigned*)Wp)[i];
        }
        *(unsigned*)&Wl[r * 136 + cc * 2] = pk;
    }
    __syncthreads();

    int wave = tid >> 6, lane = tid & 63;
    int nb = blockIdx.x * 64 + wave * 16;
    int m = lane & 15, quad = lane >> 4;
    int arow = nb + m; if (arow >= NN) arow = NN - 1;
    const unsigned short* arp = Yb + arow * DD + quad * 8;

    ffrag acc[8];
    #pragma unroll
    for (int t = 0; t < 8; ++t) acc[t] = (ffrag){0.f, 0.f, 0.f, 0.f};

    #pragma unroll
    for (int c = 0; c < 4; ++c) {
        bfrag af = *(const bfrag*)(arp + c * 32);
        #pragma unroll
        for (int t = 0; t < 8; ++t) {
            bfrag bf = *(const bfrag*)&Wl[(t * 16 + m) * 136 + c * 32 + quad * 8];
            acc[t] = __builtin_amdgcn_mfma_f32_16x16x32_bf16(af, bf, acc[t], 0, 0, 0);
        }
    }

    #pragma unroll
    for (int t = 0; t < 8; ++t) {
        int o = t * 16 + m;
        float bias = wf32 ? ((const float*)bp)[o] : bf2f(((const unsigned short*)bp)[o]);
        #pragma unroll
        for (int r = 0; r < 4; ++r) {
            int n = nb + quad * 4 + r;
            if (n < NN) {
                float v = acc[t][r] + bias;
                if (of32) ((float*)outp)[n * DD + o] = v;
                else      ((unsigned short*)outp)[n * DD + o] = f2bf(v);
            }
        }
    }
}

extern "C" void kernel_launch(void* const* d_in, const int* in_sizes, int n_in,
                              void* d_out, int out_size, void* d_ws, size_t ws_size,
                              hipStream_t stream) {
    const void* feat = d_in[0];
    const void* src  = d_in[1];
    const void* dst  = d_in[2];
    const void* W    = d_in[3];
    const void* b    = d_in[4];

    // ws (bytes): flags@0 | deg@32 | rowptr@200032 | cur@400064 | norm@600064 |
    //   srclist@800064 | X1/Yb@7200064 | X2@20000064 | bsum@32800064 | boff@32800864
    char* wsb = (char*)d_ws;
    int*   flags   = (int*)wsb;
    int*   deg     = (int*)(wsb + 32);
    int*   rowptr  = (int*)(wsb + 200032);
    int*   cur     = (int*)(wsb + 400064);
    float* norm    = (float*)(wsb + 600064);
    int*   srclist = (int*)(wsb + 800064);
    unsigned short* X1 = (unsigned short*)(wsb + 7200064);   // hop-1 input, then Yb
    unsigned short* X2 = (unsigned short*)(wsb + 20000064);
    int*   bsum    = (int*)(wsb + 32800064);
    int*   boff    = (int*)(wsb + 32800864);

    k_detect<<<1, 256, 0, stream>>>((const int*)src, (const int*)dst,
                                    (const unsigned short*)feat,
                                    (const unsigned short*)W, flags);
    k_zero<<<(NN + 255) / 256, 256, 0, stream>>>(deg);
    k_degree<<<(NE + 255) / 256, 256, 0, stream>>>(dst, deg, flags);
    k_bsum<<<NB, 256, 0, stream>>>(deg, bsum);
    k_scanb<<<1, 256, 0, stream>>>(bsum, boff, rowptr);
    k_scanc<<<NB, 256, 0, stream>>>(deg, boff, rowptr, cur, norm);
    k_bucketx<<<2048, 256, 0, stream>>>(src, dst, cur, srclist, flags);
    k_prescale<<<(NN * DD / 4 + 255) / 256, 256, 0, stream>>>(feat, norm, X1, flags);
    k_gather<<<(NN + 3) / 4, 256, 0, stream>>>(X1, rowptr, srclist, norm, X2, 0);
    k_gather<<<(NN + 3) / 4, 256, 0, stream>>>(X2, rowptr, srclist, norm, X1, 1);
    k_gemm2<<<(NN + 63) / 64, 256, 0, stream>>>(X1, W, b, d_out, flags);
}

// Round 9
// 274.041 us; speedup vs baseline: 4.6404x; 1.4514x over previous
//
#include <hip/hip_runtime.h>
#include <hip/hip_bf16.h>

#define NN 50000
#define NE 1600000
#define DD 128
#define NB 196        // 256-node bins: ceil(50000/256)
#define NCH 256       // edge chunks
#define PER 6250      // NE / NCH

typedef short bfrag __attribute__((ext_vector_type(8)));   // 8 bf16 = 4 VGPR
typedef float ffrag __attribute__((ext_vector_type(4)));   // 4 f32 acc

__device__ __forceinline__ float bf2f(unsigned short u) {
    union { unsigned int i; float f; } c; c.i = ((unsigned int)u) << 16; return c.f;
}
__device__ __forceinline__ unsigned short f2bf(float f) {
    __hip_bfloat16 h = __float2bfloat16(f);
    union { __hip_bfloat16 h; unsigned short u; } c; c.h = h; return c.u;
}
__device__ __forceinline__ int insane_bf16(unsigned short u) {
    unsigned e = (u >> 7) & 0xFF;
    return (e == 0xFF) || (e >= 0x8E);
}

// flags[0]=indices int64; flags[1]=feat f32 (=> out f32); flags[2]=W f32
__global__ void k_detect(const int* __restrict__ srcw, const int* __restrict__ dstw,
                         const unsigned short* __restrict__ feat16,
                         const unsigned short* __restrict__ w16,
                         int* __restrict__ flags) {
    __shared__ int s_idx, s_feat, s_w;
    int tid = threadIdx.x;
    if (tid == 0) { s_idx = 0; s_feat = 0; s_w = 0; }
    __syncthreads();
    if (tid < 64) {
        int v = srcw[2 * tid + 1] | dstw[2 * tid + 1];
        if (v) atomicOr(&s_idx, 1);
    }
    if (insane_bf16(feat16[2 * tid]) || insane_bf16(feat16[2 * tid + 512]))
        atomicOr(&s_feat, 1);
    if (insane_bf16(w16[2 * tid]) || insane_bf16(w16[2 * tid + 512]))
        atomicOr(&s_w, 1);
    __syncthreads();
    if (tid == 0) { flags[0] = (s_idx == 0) ? 1 : 0; flags[1] = s_feat; flags[2] = s_w; }
}

__device__ __forceinline__ int load_idx(const void* p, int e, int is64) {
    long long v = is64 ? ((const long long*)p)[e] : (long long)((const int*)p)[e];
    int i = (int)v;
    return (i < 0) ? 0 : (i >= NN ? NN - 1 : i);
}

// chunk-block counts its edges per bin
__global__ __launch_bounds__(256) void k_count(const void* __restrict__ dst,
        int* __restrict__ cnt, const int* __restrict__ flags) {
    __shared__ int lc[NB];
    int c = blockIdx.x, tid = threadIdx.x;
    if (tid < NB) lc[tid] = 0;
    __syncthreads();
    int lo = c * PER, hi = lo + PER; if (hi > NE) hi = NE;
    int is64 = flags[0];
    for (int e = lo + tid; e < hi; e += 256)
        atomicAdd(&lc[load_idx(dst, e, is64) >> 8], 1);
    __syncthreads();
    if (tid < NB) cnt[tid * NCH + c] = lc[tid];
}

// per-bin exclusive scan over chunks
__global__ __launch_bounds__(256) void k_scan2(const int* __restrict__ cnt,
        int* __restrict__ loff, int* __restrict__ binsum) {
    __shared__ int buf[256];
    int b = blockIdx.x, tid = threadIdx.x;
    int v = cnt[b * NCH + tid];
    buf[tid] = v;
    __syncthreads();
    for (int off = 1; off < 256; off <<= 1) {
        int t = (tid >= off) ? buf[tid - off] : 0;
        __syncthreads();
        buf[tid] += t;
        __syncthreads();
    }
    loff[b * NCH + tid] = buf[tid] - v;
    if (tid == 255) binsum[b] = buf[255];
}

// scan bin totals -> binoff[0..NB]; rowptr[NN]=NE
__global__ __launch_bounds__(256) void k_scanbin(const int* __restrict__ binsum,
        int* __restrict__ binoff, int* __restrict__ rowptr) {
    __shared__ int buf[256];
    int tid = threadIdx.x;
    int v = (tid < NB) ? binsum[tid] : 0;
    buf[tid] = v;
    __syncthreads();
    for (int off = 1; off < 256; off <<= 1) {
        int t = (tid >= off) ? buf[tid - off] : 0;
        __syncthreads();
        buf[tid] += t;
        __syncthreads();
    }
    if (tid < NB) binoff[tid] = buf[tid] - v;
    if (tid == NB - 1) binoff[NB] = buf[tid];
    if (tid == 0) rowptr[NN] = NE;
}

// chunk-block places edges into bin-major staged[] via precomputed offsets (no global atomics)
__global__ __launch_bounds__(256) void k_stage(const void* __restrict__ src,
        const void* __restrict__ dst, const int* __restrict__ binoff,
        const int* __restrict__ loff, unsigned* __restrict__ staged,
        const int* __restrict__ flags) {
    __shared__ int cur[NB];
    int c = blockIdx.x, tid = threadIdx.x;
    if (tid < NB) cur[tid] = binoff[tid] + loff[tid * NCH + c];
    __syncthreads();
    int lo = c * PER, hi = lo + PER; if (hi > NE) hi = NE;
    int is64 = flags[0];
    for (int e = lo + tid; e < hi; e += 256) {
        int d = load_idx(dst, e, is64);
        int s = load_idx(src, e, is64);
        int pos = atomicAdd(&cur[d >> 8], 1);
        staged[pos] = ((unsigned)(d & 255) << 16) | (unsigned)s;
    }
}

// bin-block: LDS degree count -> local scan -> rowptr/norm -> scatter into its
// private srclist window (single-writer per line => ~1x writeback)
__global__ __launch_bounds__(512) void k_fill(const unsigned* __restrict__ staged,
        const int* __restrict__ binoff, int* __restrict__ rowptr,
        float* __restrict__ norm, int* __restrict__ srclist) {
    __shared__ int ldeg[256], lrp[256];
    int b = blockIdx.x, tid = threadIdx.x;
    int lo = binoff[b], hi = binoff[b + 1];
    if (tid < 256) ldeg[tid] = 0;
    __syncthreads();
    for (int k = lo + tid; k < hi; k += 512)
        atomicAdd(&ldeg[staged[k] >> 16], 1);
    __syncthreads();
    if (tid < 256) lrp[tid] = ldeg[tid];
    __syncthreads();
    for (int off = 1; off < 256; off <<= 1) {
        int t = 0;
        if (tid < 256 && tid >= off) t = lrp[tid - off];
        __syncthreads();
        if (tid < 256) lrp[tid] += t;
        __syncthreads();
    }
    if (tid < 256) {
        int n = b * 256 + tid;
        int start = lo + lrp[tid] - ldeg[tid];   // exclusive
        if (n < NN) {
            rowptr[n] = start;
            norm[n] = rsqrtf(fmaxf((float)ldeg[tid], 1.0f));
        }
        lrp[tid] = start;                         // reuse as cursor
    }
    __syncthreads();
    for (int k = lo + tid; k < hi; k += 512) {
        unsigned u = staged[k];
        int pos = atomicAdd(&lrp[u >> 16], 1);
        srclist[pos] = (int)(u & 0xffff);
    }
}

// X1[n,d] = feat[n,d] * norm[n]  (bf16)
__global__ void k_prescale(const void* __restrict__ feat,
                           const float* __restrict__ norm,
                           unsigned short* __restrict__ X,
                           const int* __restrict__ flags) {
    int i = blockIdx.x * 256 + threadIdx.x;
    if (i >= NN * DD / 4) return;
    float nm = norm[i >> 5];
    float4 v;
    if (flags[1]) {
        v = ((const float4*)feat)[i];
    } else {
        ushort4 f = ((const ushort4*)feat)[i];
        v.x = bf2f(f.x); v.y = bf2f(f.y); v.z = bf2f(f.z); v.w = bf2f(f.w);
    }
    ushort4 o;
    o.x = f2bf(v.x * nm); o.y = f2bf(v.y * nm);
    o.z = f2bf(v.z * nm); o.w = f2bf(v.w * nm);
    ((ushort4*)X)[i] = o;
}

__device__ __forceinline__ void acc8(float* a, uint4 v) {
    a[0] += bf2f((unsigned short)(v.x & 0xffff));
    a[1] += bf2f((unsigned short)(v.x >> 16));
    a[2] += bf2f((unsigned short)(v.y & 0xffff));
    a[3] += bf2f((unsigned short)(v.y >> 16));
    a[4] += bf2f((unsigned short)(v.z & 0xffff));
    a[5] += bf2f((unsigned short)(v.z >> 16));
    a[6] += bf2f((unsigned short)(v.w & 0xffff));
    a[7] += bf2f((unsigned short)(v.w >> 16));
}

// gather-reduce: one wave per dst node; 4 edge-slots x 16 lanes x 16B rows.
// mode 0: out = bf16(acc * norm^2) -> X2;  mode 1: out = bf16(acc * norm) -> Yb
__global__ __launch_bounds__(256) void k_gather(const unsigned short* __restrict__ Xin,
        const int* __restrict__ rowptr, const int* __restrict__ srclist,
        const float* __restrict__ norm, unsigned short* __restrict__ outp,
        int mode) {
    int wid = (blockIdx.x * 256 + threadIdx.x) >> 6;
    int lane = threadIdx.x & 63;
    if (wid >= NN) return;
    int beg = rowptr[wid], end = rowptr[wid + 1];
    int g = lane >> 4;
    int c8 = (lane & 15) << 3;
    const unsigned short* xb = Xin + c8;
    float a[8];
    #pragma unroll
    for (int k = 0; k < 8; ++k) a[k] = 0.f;

    for (int j = beg + g; j < end; j += 8) {
        int s0 = srclist[j];
        uint4 v0 = *(const uint4*)(xb + s0 * DD);
        int j2 = j + 4;
        if (j2 < end) {
            int s1 = srclist[j2];
            uint4 v1 = *(const uint4*)(xb + s1 * DD);
            acc8(a, v0);
            acc8(a, v1);
        } else {
            acc8(a, v0);
        }
    }
    #pragma unroll
    for (int k = 0; k < 8; ++k) {
        a[k] += __shfl_xor(a[k], 16);
        a[k] += __shfl_xor(a[k], 32);
    }

    if (g == 0) {
        float nm = norm[wid];
        float sc = (mode == 0) ? nm * nm : nm;
        uint4 o;
        o.x = ((unsigned)f2bf(a[1] * sc) << 16) | (unsigned)f2bf(a[0] * sc);
        o.y = ((unsigned)f2bf(a[3] * sc) << 16) | (unsigned)f2bf(a[2] * sc);
        o.z = ((unsigned)f2bf(a[5] * sc) << 16) | (unsigned)f2bf(a[4] * sc);
        o.w = ((unsigned)f2bf(a[7] * sc) << 16) | (unsigned)f2bf(a[6] * sc);
        *(uint4*)(outp + wid * DD + c8) = o;
    }
}

// MFMA GEMM: out[n,o] = Yb[n,:] @ W[o,:] + b[o].  Yb bf16 (norm applied).
__global__ __launch_bounds__(256) void k_gemm2(const unsigned short* __restrict__ Yb,
        const void* __restrict__ Wp, const void* __restrict__ bp,
        void* __restrict__ outp, const int* __restrict__ flags) {
    __shared__ unsigned short Wl[DD * 136];
    int tid = threadIdx.x;
    int wf32 = flags[2], of32 = flags[1];

    for (int i = tid; i < 8192; i += 256) {
        int r = i >> 6, cc = i & 63;
        unsigned pk;
        if (wf32) {
            float2 w = ((const float2*)Wp)[i];
            pk = ((unsigned)f2bf(w.y) << 16) | (unsigned)f2bf(w.x);
        } else {
            pk = ((const unsigned*)Wp)[i];
        }
        *(unsigned*)&Wl[r * 136 + cc * 2] = pk;
    }
    __syncthreads();

    int wave = tid >> 6, lane = tid & 63;
    int nb = blockIdx.x * 64 + wave * 16;
    int m = lane & 15, quad = lane >> 4;
    int arow = nb + m; if (arow >= NN) arow = NN - 1;
    const unsigned short* arp = Yb + arow * DD + quad * 8;

    ffrag acc[8];
    #pragma unroll
    for (int t = 0; t < 8; ++t) acc[t] = (ffrag){0.f, 0.f, 0.f, 0.f};

    #pragma unroll
    for (int c = 0; c < 4; ++c) {
        bfrag af = *(const bfrag*)(arp + c * 32);
        #pragma unroll
        for (int t = 0; t < 8; ++t) {
            bfrag bf = *(const bfrag*)&Wl[(t * 16 + m) * 136 + c * 32 + quad * 8];
            acc[t] = __builtin_amdgcn_mfma_f32_16x16x32_bf16(af, bf, acc[t], 0, 0, 0);
        }
    }

    #pragma unroll
    for (int t = 0; t < 8; ++t) {
        int o = t * 16 + m;
        float bias = wf32 ? ((const float*)bp)[o] : bf2f(((const unsigned short*)bp)[o]);
        #pragma unroll
        for (int r = 0; r < 4; ++r) {
            int n = nb + quad * 4 + r;
            if (n < NN) {
                float v = acc[t][r] + bias;
                if (of32) ((float*)outp)[n * DD + o] = v;
                else      ((unsigned short*)outp)[n * DD + o] = f2bf(v);
            }
        }
    }
}

extern "C" void kernel_launch(void* const* d_in, const int* in_sizes, int n_in,
                              void* d_out, int out_size, void* d_ws, size_t ws_size,
                              hipStream_t stream) {
    const void* feat = d_in[0];
    const void* src  = d_in[1];
    const void* dst  = d_in[2];
    const void* W    = d_in[3];
    const void* b    = d_in[4];

    // ws (bytes): flags@0 | rowptr@64 | norm@200128 | cnt@400128 | loff@600832 |
    //   binsum@801536 | binoff@802560 | srclist@803584 | X1@7203584 | X2@20003584
    //   staged aliases X2's first 6.4MB (dead before gather-0 writes X2). end 32.8MB
    char* wsb = (char*)d_ws;
    int*   flags   = (int*)wsb;
    int*   rowptr  = (int*)(wsb + 64);
    float* norm    = (float*)(wsb + 200128);
    int*   cnt     = (int*)(wsb + 400128);
    int*   loff    = (int*)(wsb + 600832);
    int*   binsum  = (int*)(wsb + 801536);
    int*   binoff  = (int*)(wsb + 802560);
    int*   srclist = (int*)(wsb + 803584);
    unsigned short* X1 = (unsigned short*)(wsb + 7203584);   // hop-1 input, then Yb
    unsigned short* X2 = (unsigned short*)(wsb + 20003584);
    unsigned* staged   = (unsigned*)(wsb + 20003584);

    k_detect<<<1, 256, 0, stream>>>((const int*)src, (const int*)dst,
                                    (const unsigned short*)feat,
                                    (const unsigned short*)W, flags);
    k_count<<<NCH, 256, 0, stream>>>(dst, cnt, flags);
    k_scan2<<<NB, 256, 0, stream>>>(cnt, loff, binsum);
    k_scanbin<<<1, 256, 0, stream>>>(binsum, binoff, rowptr);
    k_stage<<<NCH, 256, 0, stream>>>(src, dst, binoff, loff, staged, flags);
    k_fill<<<NB, 512, 0, stream>>>(staged, binoff, rowptr, norm, srclist);
    k_prescale<<<(NN * DD / 4 + 255) / 256, 256, 0, stream>>>(feat, norm, X1, flags);
    k_gather<<<(NN + 3) / 4, 256, 0, stream>>>(X1, rowptr, srclist, norm, X2, 0);
    k_gather<<<(NN + 3) / 4, 256, 0, stream>>>(X2, rowptr, srclist, norm, X1, 1);
    k_gemm2<<<(NN + 63) / 64, 256, 0, stream>>>(X1, W, b, d_out, flags);
}

// Round 10
// 269.962 us; speedup vs baseline: 4.7105x; 1.0151x over previous
//
#include <hip/hip_runtime.h>
#include <hip/hip_bf16.h>

#define NN 50000
#define NE 1600000
#define DD 128
#define NB 196        // 256-node bins: ceil(50000/256)
#define NCH 256       // edge chunks
#define PER 6250      // NE / NCH
#define NT 4          // src tiles
#define TS 12500      // nodes per src tile (3.2 MB of X rows < 4 MB XCD L2)

typedef short bfrag __attribute__((ext_vector_type(8)));   // 8 bf16 = 4 VGPR
typedef float ffrag __attribute__((ext_vector_type(4)));   // 4 f32 acc

__device__ __forceinline__ float bf2f(unsigned short u) {
    union { unsigned int i; float f; } c; c.i = ((unsigned int)u) << 16; return c.f;
}
__device__ __forceinline__ unsigned short f2bf(float f) {
    __hip_bfloat16 h = __float2bfloat16(f);
    union { __hip_bfloat16 h; unsigned short u; } c; c.h = h; return c.u;
}
__device__ __forceinline__ int insane_bf16(unsigned short u) {
    unsigned e = (u >> 7) & 0xFF;
    return (e == 0xFF) || (e >= 0x8E);
}

// flags[0]=indices int64; flags[1]=feat f32 (=> out f32); flags[2]=W f32
__global__ void k_detect(const int* __restrict__ srcw, const int* __restrict__ dstw,
                         const unsigned short* __restrict__ feat16,
                         const unsigned short* __restrict__ w16,
                         int* __restrict__ flags) {
    __shared__ int s_idx, s_feat, s_w;
    int tid = threadIdx.x;
    if (tid == 0) { s_idx = 0; s_feat = 0; s_w = 0; }
    __syncthreads();
    if (tid < 64) {
        int v = srcw[2 * tid + 1] | dstw[2 * tid + 1];
        if (v) atomicOr(&s_idx, 1);
    }
    if (insane_bf16(feat16[2 * tid]) || insane_bf16(feat16[2 * tid + 512]))
        atomicOr(&s_feat, 1);
    if (insane_bf16(w16[2 * tid]) || insane_bf16(w16[2 * tid + 512]))
        atomicOr(&s_w, 1);
    __syncthreads();
    if (tid == 0) { flags[0] = (s_idx == 0) ? 1 : 0; flags[1] = s_feat; flags[2] = s_w; }
}

__device__ __forceinline__ int load_idx(const void* p, int e, int is64) {
    long long v = is64 ? ((const long long*)p)[e] : (long long)((const int*)p)[e];
    int i = (int)v;
    return (i < 0) ? 0 : (i >= NN ? NN - 1 : i);
}

// chunk-block counts its edges per bin
__global__ __launch_bounds__(256) void k_count(const void* __restrict__ dst,
        int* __restrict__ cnt, const int* __restrict__ flags) {
    __shared__ int lc[NB];
    int c = blockIdx.x, tid = threadIdx.x;
    if (tid < NB) lc[tid] = 0;
    __syncthreads();
    int lo = c * PER, hi = lo + PER; if (hi > NE) hi = NE;
    int is64 = flags[0];
    for (int e = lo + tid; e < hi; e += 256)
        atomicAdd(&lc[load_idx(dst, e, is64) >> 8], 1);
    __syncthreads();
    if (tid < NB) cnt[tid * NCH + c] = lc[tid];
}

// per-bin exclusive scan over chunks
__global__ __launch_bounds__(256) void k_scan2(const int* __restrict__ cnt,
        int* __restrict__ loff, int* __restrict__ binsum) {
    __shared__ int buf[256];
    int b = blockIdx.x, tid = threadIdx.x;
    int v = cnt[b * NCH + tid];
    buf[tid] = v;
    __syncthreads();
    for (int off = 1; off < 256; off <<= 1) {
        int t = (tid >= off) ? buf[tid - off] : 0;
        __syncthreads();
        buf[tid] += t;
        __syncthreads();
    }
    loff[b * NCH + tid] = buf[tid] - v;
    if (tid == 255) binsum[b] = buf[255];
}

// scan bin totals -> binoff[0..NB]; rowptr[NN]=NE
__global__ __launch_bounds__(256) void k_scanbin(const int* __restrict__ binsum,
        int* __restrict__ binoff, int* __restrict__ rowptr) {
    __shared__ int buf[256];
    int tid = threadIdx.x;
    int v = (tid < NB) ? binsum[tid] : 0;
    buf[tid] = v;
    __syncthreads();
    for (int off = 1; off < 256; off <<= 1) {
        int t = (tid >= off) ? buf[tid - off] : 0;
        __syncthreads();
        buf[tid] += t;
        __syncthreads();
    }
    if (tid < NB) binoff[tid] = buf[tid] - v;
    if (tid == NB - 1) binoff[NB] = buf[tid];
    if (tid == 0) rowptr[NN] = NE;
}

// chunk-block places edges into bin-major staged[] via precomputed offsets
__global__ __launch_bounds__(256) void k_stage(const void* __restrict__ src,
        const void* __restrict__ dst, const int* __restrict__ binoff,
        const int* __restrict__ loff, unsigned* __restrict__ staged,
        const int* __restrict__ flags) {
    __shared__ int cur[NB];
    int c = blockIdx.x, tid = threadIdx.x;
    if (tid < NB) cur[tid] = binoff[tid] + loff[tid * NCH + c];
    __syncthreads();
    int lo = c * PER, hi = lo + PER; if (hi > NE) hi = NE;
    int is64 = flags[0];
    for (int e = lo + tid; e < hi; e += 256) {
        int d = load_idx(dst, e, is64);
        int s = load_idx(src, e, is64);
        int pos = atomicAdd(&cur[d >> 8], 1);
        staged[pos] = ((unsigned)(d & 255) << 16) | (unsigned)s;
    }
}

// bin-block: (node,tile) LDS count -> scan -> rowptr/norm -> tile-grouped scatter
// into its private srclist window. srclist per node is grouped by src tile so
// the gather's reads sweep 3.2MB tiles (per-XCD-L2-resident).
__global__ __launch_bounds__(512) void k_fill(const unsigned* __restrict__ staged,
        const int* __restrict__ binoff, int* __restrict__ rowptr,
        float* __restrict__ norm, int* __restrict__ srclist) {
    __shared__ int cnt4[256 * NT];   // (node,tile) counts, then cursors
    __shared__ int ntot[256];        // node totals -> inclusive scan
    int b = blockIdx.x, tid = threadIdx.x;
    int lo = binoff[b], hi = binoff[b + 1];
    for (int i = tid; i < 256 * NT; i += 512) cnt4[i] = 0;
    __syncthreads();
    for (int k = lo + tid; k < hi; k += 512) {
        unsigned u = staged[k];
        int nl = u >> 16;
        int s = (int)(u & 0xffff);
        atomicAdd(&cnt4[nl * NT + s / TS], 1);
    }
    __syncthreads();
    if (tid < 256)
        ntot[tid] = cnt4[tid * NT] + cnt4[tid * NT + 1]
                  + cnt4[tid * NT + 2] + cnt4[tid * NT + 3];
    __syncthreads();
    for (int off = 1; off < 256; off <<= 1) {
        int t = 0;
        if (tid < 256 && tid >= off) t = ntot[tid - off];
        __syncthreads();
        if (tid < 256) ntot[tid] += t;
        __syncthreads();
    }
    if (tid < 256) {
        int v0 = cnt4[tid * NT], v1 = cnt4[tid * NT + 1];
        int v2 = cnt4[tid * NT + 2], v3 = cnt4[tid * NT + 3];
        int deg = v0 + v1 + v2 + v3;
        int start = lo + ntot[tid] - deg;     // exclusive prefix
        int n = b * 256 + tid;
        if (n < NN) {
            rowptr[n] = start;
            norm[n] = rsqrtf(fmaxf((float)deg, 1.0f));
        }
        int c = start;
        cnt4[tid * NT + 0] = c; c += v0;
        cnt4[tid * NT + 1] = c; c += v1;
        cnt4[tid * NT + 2] = c; c += v2;
        cnt4[tid * NT + 3] = c;
    }
    __syncthreads();
    for (int k = lo + tid; k < hi; k += 512) {
        unsigned u = staged[k];
        int nl = u >> 16;
        int s = (int)(u & 0xffff);
        int pos = atomicAdd(&cnt4[nl * NT + s / TS], 1);
        srclist[pos] = s;
    }
}

// X1[n,d] = feat[n,d] * norm[n]  (bf16)
__global__ void k_prescale(const void* __restrict__ feat,
                           const float* __restrict__ norm,
                           unsigned short* __restrict__ X,
                           const int* __restrict__ flags) {
    int i = blockIdx.x * 256 + threadIdx.x;
    if (i >= NN * DD / 4) return;
    float nm = norm[i >> 5];
    float4 v;
    if (flags[1]) {
        v = ((const float4*)feat)[i];
    } else {
        ushort4 f = ((const ushort4*)feat)[i];
        v.x = bf2f(f.x); v.y = bf2f(f.y); v.z = bf2f(f.z); v.w = bf2f(f.w);
    }
    ushort4 o;
    o.x = f2bf(v.x * nm); o.y = f2bf(v.y * nm);
    o.z = f2bf(v.z * nm); o.w = f2bf(v.w * nm);
    ((ushort4*)X)[i] = o;
}

__device__ __forceinline__ void acc8(float* a, uint4 v) {
    a[0] += bf2f((unsigned short)(v.x & 0xffff));
    a[1] += bf2f((unsigned short)(v.x >> 16));
    a[2] += bf2f((unsigned short)(v.y & 0xffff));
    a[3] += bf2f((unsigned short)(v.y >> 16));
    a[4] += bf2f((unsigned short)(v.z & 0xffff));
    a[5] += bf2f((unsigned short)(v.z >> 16));
    a[6] += bf2f((unsigned short)(v.w & 0xffff));
    a[7] += bf2f((unsigned short)(v.w >> 16));
}

// gather-reduce: one wave per dst node; 4 edge-slots x 16 lanes x 16B rows.
// mode 0: out = bf16(acc * norm^2) -> X2;  mode 1: out = bf16(acc * norm) -> Yb
__global__ __launch_bounds__(256) void k_gather(const unsigned short* __restrict__ Xin,
        const int* __restrict__ rowptr, const int* __restrict__ srclist,
        const float* __restrict__ norm, unsigned short* __restrict__ outp,
        int mode) {
    int wid = (blockIdx.x * 256 + threadIdx.x) >> 6;
    int lane = threadIdx.x & 63;
    if (wid >= NN) return;
    int beg = rowptr[wid], end = rowptr[wid + 1];
    int g = lane >> 4;
    int c8 = (lane & 15) << 3;
    const unsigned short* xb = Xin + c8;
    float a[8];
    #pragma unroll
    for (int k = 0; k < 8; ++k) a[k] = 0.f;

    for (int j = beg + g; j < end; j += 8) {
        int s0 = srclist[j];
        uint4 v0 = *(const uint4*)(xb + s0 * DD);
        int j2 = j + 4;
        if (j2 < end) {
            int s1 = srclist[j2];
            uint4 v1 = *(const uint4*)(xb + s1 * DD);
            acc8(a, v0);
            acc8(a, v1);
        } else {
            acc8(a, v0);
        }
    }
    #pragma unroll
    for (int k = 0; k < 8; ++k) {
        a[k] += __shfl_xor(a[k], 16);
        a[k] += __shfl_xor(a[k], 32);
    }

    if (g == 0) {
        float nm = norm[wid];
        float sc = (mode == 0) ? nm * nm : nm;
        uint4 o;
        o.x = ((unsigned)f2bf(a[1] * sc) << 16) | (unsigned)f2bf(a[0] * sc);
        o.y = ((unsigned)f2bf(a[3] * sc) << 16) | (unsigned)f2bf(a[2] * sc);
        o.z = ((unsigned)f2bf(a[5] * sc) << 16) | (unsigned)f2bf(a[4] * sc);
        o.w = ((unsigned)f2bf(a[7] * sc) << 16) | (unsigned)f2bf(a[6] * sc);
        *(uint4*)(outp + wid * DD + c8) = o;
    }
}

// MFMA GEMM: out[n,o] = Yb[n,:] @ W[o,:] + b[o].  Yb bf16 (norm applied).
__global__ __launch_bounds__(256) void k_gemm2(const unsigned short* __restrict__ Yb,
        const void* __restrict__ Wp, const void* __restrict__ bp,
        void* __restrict__ outp, const int* __restrict__ flags) {
    __shared__ unsigned short Wl[DD * 136];
    int tid = threadIdx.x;
    int wf32 = flags[2], of32 = flags[1];

    for (int i = tid; i < 8192; i += 256) {
        int r = i >> 6, cc = i & 63;
        unsigned pk;
        if (wf32) {
            float2 w = ((const float2*)Wp)[i];
            pk = ((unsigned)f2bf(w.y) << 16) | (unsigned)f2bf(w.x);
        } else {
            pk = ((const unsigned*)Wp)[i];
        }
        *(unsigned*)&Wl[r * 136 + cc * 2] = pk;
    }
    __syncthreads();

    int wave = tid >> 6, lane = tid & 63;
    int nb = blockIdx.x * 64 + wave * 16;
    int m = lane & 15, quad = lane >> 4;
    int arow = nb + m; if (arow >= NN) arow = NN - 1;
    const unsigned short* arp = Yb + arow * DD + quad * 8;

    ffrag acc[8];
    #pragma unroll
    for (int t = 0; t < 8; ++t) acc[t] = (ffrag){0.f, 0.f, 0.f, 0.f};

    #pragma unroll
    for (int c = 0; c < 4; ++c) {
        bfrag af = *(const bfrag*)(arp + c * 32);
        #pragma unroll
        for (int t = 0; t < 8; ++t) {
            bfrag bf = *(const bfrag*)&Wl[(t * 16 + m) * 136 + c * 32 + quad * 8];
            acc[t] = __builtin_amdgcn_mfma_f32_16x16x32_bf16(af, bf, acc[t], 0, 0, 0);
        }
    }

    #pragma unroll
    for (int t = 0; t < 8; ++t) {
        int o = t * 16 + m;
        float bias = wf32 ? ((const float*)bp)[o] : bf2f(((const unsigned short*)bp)[o]);
        #pragma unroll
        for (int r = 0; r < 4; ++r) {
            int n = nb + quad * 4 + r;
            if (n < NN) {
                float v = acc[t][r] + bias;
                if (of32) ((float*)outp)[n * DD + o] = v;
                else      ((unsigned short*)outp)[n * DD + o] = f2bf(v);
            }
        }
    }
}

extern "C" void kernel_launch(void* const* d_in, const int* in_sizes, int n_in,
                              void* d_out, int out_size, void* d_ws, size_t ws_size,
                              hipStream_t stream) {
    const void* feat = d_in[0];
    const void* src  = d_in[1];
    const void* dst  = d_in[2];
    const void* W    = d_in[3];
    const void* b    = d_in[4];

    // ws (bytes): flags@0 | rowptr@64 | norm@200128 | cnt@400128 | loff@600832 |
    //   binsum@801536 | binoff@802560 | srclist@803584 | X1@7203584 | X2@20003584
    //   staged aliases X2's first 6.4MB (dead before gather-0 writes X2). end 32.8MB
    char* wsb = (char*)d_ws;
    int*   flags   = (int*)wsb;
    int*   rowptr  = (int*)(wsb + 64);
    float* norm    = (float*)(wsb + 200128);
    int*   cnt     = (int*)(wsb + 400128);
    int*   loff    = (int*)(wsb + 600832);
    int*   binsum  = (int*)(wsb + 801536);
    int*   binoff  = (int*)(wsb + 802560);
    int*   srclist = (int*)(wsb + 803584);
    unsigned short* X1 = (unsigned short*)(wsb + 7203584);   // hop-1 input, then Yb
    unsigned short* X2 = (unsigned short*)(wsb + 20003584);
    unsigned* staged   = (unsigned*)(wsb + 20003584);

    k_detect<<<1, 256, 0, stream>>>((const int*)src, (const int*)dst,
                                    (const unsigned short*)feat,
                                    (const unsigned short*)W, flags);
    k_count<<<NCH, 256, 0, stream>>>(dst, cnt, flags);
    k_scan2<<<NB, 256, 0, stream>>>(cnt, loff, binsum);
    k_scanbin<<<1, 256, 0, stream>>>(binsum, binoff, rowptr);
    k_stage<<<NCH, 256, 0, stream>>>(src, dst, binoff, loff, staged, flags);
    k_fill<<<NB, 512, 0, stream>>>(staged, binoff, rowptr, norm, srclist);
    k_prescale<<<(NN * DD / 4 + 255) / 256, 256, 0, stream>>>(feat, norm, X1, flags);
    k_gather<<<(NN + 3) / 4, 256, 0, stream>>>(X1, rowptr, srclist, norm, X2, 0);
    k_gather<<<(NN + 3) / 4, 256, 0, stream>>>(X2, rowptr, srclist, norm, X1, 1);
    k_gemm2<<<(NN + 63) / 64, 256, 0, stream>>>(X1, W, b, d_out, flags);
}

// Round 12
// 249.513 us; speedup vs baseline: 5.0966x; 1.0820x over previous
//
#include <hip/hip_runtime.h>
#include <hip/hip_bf16.h>

#define NN 50000
#define NE 1600000
#define DD 128
#define NB 196        // 256-node bins: ceil(50000/256)
#define NCH 256       // edge chunks
#define PER 6250      // NE / NCH
#define NT 4          // src tiles
#define TS 12500      // nodes per src tile

typedef short bfrag __attribute__((ext_vector_type(8)));   // 8 bf16 = 4 VGPR
typedef float ffrag __attribute__((ext_vector_type(4)));   // 4 f32 acc

__device__ __forceinline__ float bf2f(unsigned short u) {
    union { unsigned int i; float f; } c; c.i = ((unsigned int)u) << 16; return c.f;
}
__device__ __forceinline__ unsigned short f2bf(float f) {
    __hip_bfloat16 h = __float2bfloat16(f);
    union { __hip_bfloat16 h; unsigned short u; } c; c.h = h; return c.u;
}
__device__ __forceinline__ int insane_bf16(unsigned short u) {
    unsigned e = (u >> 7) & 0xFF;
    return (e == 0xFF) || (e >= 0x8E);
}

// flags[0]=indices int64; flags[1]=feat f32 (=> out f32); flags[2]=W f32
__global__ void k_detect(const int* __restrict__ srcw, const int* __restrict__ dstw,
                         const unsigned short* __restrict__ feat16,
                         const unsigned short* __restrict__ w16,
                         int* __restrict__ flags) {
    __shared__ int s_idx, s_feat, s_w;
    int tid = threadIdx.x;
    if (tid == 0) { s_idx = 0; s_feat = 0; s_w = 0; }
    __syncthreads();
    if (tid < 64) {
        int v = srcw[2 * tid + 1] | dstw[2 * tid + 1];
        if (v) atomicOr(&s_idx, 1);
    }
    if (insane_bf16(feat16[2 * tid]) || insane_bf16(feat16[2 * tid + 512]))
        atomicOr(&s_feat, 1);
    if (insane_bf16(w16[2 * tid]) || insane_bf16(w16[2 * tid + 512]))
        atomicOr(&s_w, 1);
    __syncthreads();
    if (tid == 0) { flags[0] = (s_idx == 0) ? 1 : 0; flags[1] = s_feat; flags[2] = s_w; }
}

__device__ __forceinline__ int load_idx(const void* p, int e, int is64) {
    long long v = is64 ? ((const long long*)p)[e] : (long long)((const int*)p)[e];
    int i = (int)v;
    return (i < 0) ? 0 : (i >= NN ? NN - 1 : i);
}

// chunk-block counts its edges per bin
__global__ __launch_bounds__(256) void k_count(const void* __restrict__ dst,
        int* __restrict__ cnt, const int* __restrict__ flags) {
    __shared__ int lc[NB];
    int c = blockIdx.x, tid = threadIdx.x;
    if (tid < NB) lc[tid] = 0;
    __syncthreads();
    int lo = c * PER, hi = lo + PER; if (hi > NE) hi = NE;
    int is64 = flags[0];
    for (int e = lo + tid; e < hi; e += 256)
        atomicAdd(&lc[load_idx(dst, e, is64) >> 8], 1);
    __syncthreads();
    if (tid < NB) cnt[tid * NCH + c] = lc[tid];
}

// per-bin exclusive scan over chunks
__global__ __launch_bounds__(256) void k_scan2(const int* __restrict__ cnt,
        int* __restrict__ loff, int* __restrict__ binsum) {
    __shared__ int buf[256];
    int b = blockIdx.x, tid = threadIdx.x;
    int v = cnt[b * NCH + tid];
    buf[tid] = v;
    __syncthreads();
    for (int off = 1; off < 256; off <<= 1) {
        int t = (tid >= off) ? buf[tid - off] : 0;
        __syncthreads();
        buf[tid] += t;
        __syncthreads();
    }
    loff[b * NCH + tid] = buf[tid] - v;
    if (tid == 255) binsum[b] = buf[255];
}

// scan bin totals -> binoff[0..NB]; rowptr[NN]=NE
__global__ __launch_bounds__(256) void k_scanbin(const int* __restrict__ binsum,
        int* __restrict__ binoff, int* __restrict__ rowptr) {
    __shared__ int buf[256];
    int tid = threadIdx.x;
    int v = (tid < NB) ? binsum[tid] : 0;
    buf[tid] = v;
    __syncthreads();
    for (int off = 1; off < 256; off <<= 1) {
        int t = (tid >= off) ? buf[tid - off] : 0;
        __syncthreads();
        buf[tid] += t;
        __syncthreads();
    }
    if (tid < NB) binoff[tid] = buf[tid] - v;
    if (tid == NB - 1) binoff[NB] = buf[tid];
    if (tid == 0) rowptr[NN] = NE;
}

// chunk-block places edges into bin-major staged[] via precomputed offsets
__global__ __launch_bounds__(256) void k_stage(const void* __restrict__ src,
        const void* __restrict__ dst, const int* __restrict__ binoff,
        const int* __restrict__ loff, unsigned* __restrict__ staged,
        const int* __restrict__ flags) {
    __shared__ int cur[NB];
    int c = blockIdx.x, tid = threadIdx.x;
    if (tid < NB) cur[tid] = binoff[tid] + loff[tid * NCH + c];
    __syncthreads();
    int lo = c * PER, hi = lo + PER; if (hi > NE) hi = NE;
    int is64 = flags[0];
    for (int e = lo + tid; e < hi; e += 256) {
        int d = load_idx(dst, e, is64);
        int s = load_idx(src, e, is64);
        int pos = atomicAdd(&cur[d >> 8], 1);
        staged[pos] = ((unsigned)(d & 255) << 16) | (unsigned)s;
    }
}

// bin-block: (node,tile) LDS count -> scan -> rowptr/norm -> tile-grouped scatter
__global__ __launch_bounds__(512) void k_fill(const unsigned* __restrict__ staged,
        const int* __restrict__ binoff, int* __restrict__ rowptr,
        float* __restrict__ norm, int* __restrict__ srclist) {
    __shared__ int cnt4[256 * NT];
    __shared__ int ntot[256];
    int b = blockIdx.x, tid = threadIdx.x;
    int lo = binoff[b], hi = binoff[b + 1];
    for (int i = tid; i < 256 * NT; i += 512) cnt4[i] = 0;
    __syncthreads();
    for (int k = lo + tid; k < hi; k += 512) {
        unsigned u = staged[k];
        atomicAdd(&cnt4[(u >> 16) * NT + (int)(u & 0xffff) / TS], 1);
    }
    __syncthreads();
    if (tid < 256)
        ntot[tid] = cnt4[tid * NT] + cnt4[tid * NT + 1]
                  + cnt4[tid * NT + 2] + cnt4[tid * NT + 3];
    __syncthreads();
    for (int off = 1; off < 256; off <<= 1) {
        int t = 0;
        if (tid < 256 && tid >= off) t = ntot[tid - off];
        __syncthreads();
        if (tid < 256) ntot[tid] += t;
        __syncthreads();
    }
    if (tid < 256) {
        int v0 = cnt4[tid * NT], v1 = cnt4[tid * NT + 1];
        int v2 = cnt4[tid * NT + 2], v3 = cnt4[tid * NT + 3];
        int deg = v0 + v1 + v2 + v3;
        int start = lo + ntot[tid] - deg;
        int n = b * 256 + tid;
        if (n < NN) {
            rowptr[n] = start;
            norm[n] = rsqrtf(fmaxf((float)deg, 1.0f));
        }
        int c = start;
        cnt4[tid * NT + 0] = c; c += v0;
        cnt4[tid * NT + 1] = c; c += v1;
        cnt4[tid * NT + 2] = c; c += v2;
        cnt4[tid * NT + 3] = c;
    }
    __syncthreads();
    for (int k = lo + tid; k < hi; k += 512) {
        unsigned u = staged[k];
        int pos = atomicAdd(&cnt4[(u >> 16) * NT + (int)(u & 0xffff) / TS], 1);
        srclist[pos] = (int)(u & 0xffff);
    }
}

// X1[n,d] = feat[n,d] * norm[n]  (bf16)
__global__ void k_prescale(const void* __restrict__ feat,
                           const float* __restrict__ norm,
                           unsigned short* __restrict__ X,
                           const int* __restrict__ flags) {
    int i = blockIdx.x * 256 + threadIdx.x;
    if (i >= NN * DD / 4) return;
    float nm = norm[i >> 5];
    float4 v;
    if (flags[1]) {
        v = ((const float4*)feat)[i];
    } else {
        ushort4 f = ((const ushort4*)feat)[i];
        v.x = bf2f(f.x); v.y = bf2f(f.y); v.z = bf2f(f.z); v.w = bf2f(f.w);
    }
    ushort4 o;
    o.x = f2bf(v.x * nm); o.y = f2bf(v.y * nm);
    o.z = f2bf(v.z * nm); o.w = f2bf(v.w * nm);
    ((ushort4*)X)[i] = o;
}

__device__ __forceinline__ void acc8(float* a, uint4 v) {
    a[0] += bf2f((unsigned short)(v.x & 0xffff));
    a[1] += bf2f((unsigned short)(v.x >> 16));
    a[2] += bf2f((unsigned short)(v.y & 0xffff));
    a[3] += bf2f((unsigned short)(v.y >> 16));
    a[4] += bf2f((unsigned short)(v.z & 0xffff));
    a[5] += bf2f((unsigned short)(v.z >> 16));
    a[6] += bf2f((unsigned short)(v.w & 0xffff));
    a[7] += bf2f((unsigned short)(v.w >> 16));
}

// gather-reduce: one wave per dst node; 4 edge-slots x 16 lanes x 16B rows.
// Slot g walks j = beg+g (mod 4); 4 independent row loads in flight per lane.
// mode 0: out = bf16(acc * norm^2) -> X2;  mode 1: out = bf16(acc * norm) -> Yb
__global__ __launch_bounds__(256) void k_gather(const unsigned short* __restrict__ Xin,
        const int* __restrict__ rowptr, const int* __restrict__ srclist,
        const float* __restrict__ norm, unsigned short* __restrict__ outp,
        int mode) {
    int wid = (blockIdx.x * 256 + threadIdx.x) >> 6;
    int lane = threadIdx.x & 63;
    if (wid >= NN) return;
    int beg = rowptr[wid], end = rowptr[wid + 1];
    int g = lane >> 4;
    int c8 = (lane & 15) << 3;
    const unsigned short* xb = Xin + c8;
    float a[8];
    #pragma unroll
    for (int k = 0; k < 8; ++k) a[k] = 0.f;

    int j = beg + g;
    for (; j + 12 < end; j += 16) {
        int s0 = srclist[j];
        int s1 = srclist[j + 4];
        int s2 = srclist[j + 8];
        int s3 = srclist[j + 12];
        uint4 v0 = *(const uint4*)(xb + s0 * DD);
        uint4 v1 = *(const uint4*)(xb + s1 * DD);
        uint4 v2 = *(const uint4*)(xb + s2 * DD);
        uint4 v3 = *(const uint4*)(xb + s3 * DD);
        acc8(a, v0); acc8(a, v1); acc8(a, v2); acc8(a, v3);
    }
    for (; j < end; j += 4) {
        int s = srclist[j];
        uint4 v = *(const uint4*)(xb + s * DD);
        acc8(a, v);
    }
    #pragma unroll
    for (int k = 0; k < 8; ++k) {
        a[k] += __shfl_xor(a[k], 16);
        a[k] += __shfl_xor(a[k], 32);
    }

    if (g == 0) {
        float nm = norm[wid];
        float sc = (mode == 0) ? nm * nm : nm;
        uint4 o;
        o.x = ((unsigned)f2bf(a[1] * sc) << 16) | (unsigned)f2bf(a[0] * sc);
        o.y = ((unsigned)f2bf(a[3] * sc) << 16) | (unsigned)f2bf(a[2] * sc);
        o.z = ((unsigned)f2bf(a[5] * sc) << 16) | (unsigned)f2bf(a[4] * sc);
        o.w = ((unsigned)f2bf(a[7] * sc) << 16) | (unsigned)f2bf(a[6] * sc);
        *(uint4*)(outp + wid * DD + c8) = o;
    }
}

// MFMA GEMM: out[n,o] = Yb[n,:] @ W[o,:] + b[o].  Yb bf16 (norm applied).
__global__ __launch_bounds__(256) void k_gemm2(const unsigned short* __restrict__ Yb,
        const void* __restrict__ Wp, const void* __restrict__ bp,
        void* __restrict__ outp, const int* __restrict__ flags) {
    __shared__ unsigned short Wl[DD * 136];
    int tid = threadIdx.x;
    int wf32 = flags[2], of32 = flags[1];

    for (int i = tid; i < 8192; i += 256) {
        int r = i >> 6, cc = i & 63;
        unsigned pk;
        if (wf32) {
            float2 w = ((const float2*)Wp)[i];
            pk = ((unsigned)f2bf(w.y) << 16) | (unsigned)f2bf(w.x);
        } else {
            pk = ((const unsigned*)Wp)[i];
        }
        *(unsigned*)&Wl[r * 136 + cc * 2] = pk;
    }
    __syncthreads();

    int wave = tid >> 6, lane = tid & 63;
    int nb = blockIdx.x * 64 + wave * 16;
    int m = lane & 15, quad = lane >> 4;
    int arow = nb + m; if (arow >= NN) arow = NN - 1;
    const unsigned short* arp = Yb + arow * DD + quad * 8;

    ffrag acc[8];
    #pragma unroll
    for (int t = 0; t < 8; ++t) acc[t] = (ffrag){0.f, 0.f, 0.f, 0.f};

    #pragma unroll
    for (int c = 0; c < 4; ++c) {
        bfrag af = *(const bfrag*)(arp + c * 32);
        #pragma unroll
        for (int t = 0; t < 8; ++t) {
            bfrag bf = *(const bfrag*)&Wl[(t * 16 + m) * 136 + c * 32 + quad * 8];
            acc[t] = __builtin_amdgcn_mfma_f32_16x16x32_bf16(af, bf, acc[t], 0, 0, 0);
        }
    }

    #pragma unroll
    for (int t = 0; t < 8; ++t) {
        int o = t * 16 + m;
        float bias = wf32 ? ((const float*)bp)[o] : bf2f(((const unsigned short*)bp)[o]);
        #pragma unroll
        for (int r = 0; r < 4; ++r) {
            int n = nb + quad * 4 + r;
            if (n < NN) {
                float v = acc[t][r] + bias;
                if (of32) ((float*)outp)[n * DD + o] = v;
                else      ((unsigned short*)outp)[n * DD + o] = f2bf(v);
            }
        }
    }
}

extern "C" void kernel_launch(void* const* d_in, const int* in_sizes, int n_in,
                              void* d_out, int out_size, void* d_ws, size_t ws_size,
                              hipStream_t stream) {
    const void* feat = d_in[0];
    const void* src  = d_in[1];
    const void* dst  = d_in[2];
    const void* W    = d_in[3];
    const void* b    = d_in[4];

    // ws (bytes): flags@0 | rowptr@64 | norm@200128 | cnt@400128 | loff@600832 |
    //   binsum@801536 | binoff@802560 | srclist@803584 | X1@7203584 | X2@20003584
    //   staged aliases X2's first 6.4MB (dead before gather-0 writes X2). end 32.8MB
    char* wsb = (char*)d_ws;
    int*   flags   = (int*)wsb;
    int*   rowptr  = (int*)(wsb + 64);
    float* norm    = (float*)(wsb + 200128);
    int*   cnt     = (int*)(wsb + 400128);
    int*   loff    = (int*)(wsb + 600832);
    int*   binsum  = (int*)(wsb + 801536);
    int*   binoff  = (int*)(wsb + 802560);
    int*   srclist = (int*)(wsb + 803584);
    unsigned short* X1 = (unsigned short*)(wsb + 7203584);   // hop-1 input, then Yb
    unsigned short* X2 = (unsigned short*)(wsb + 20003584);
    unsigned* staged   = (unsigned*)(wsb + 20003584);

    k_detect<<<1, 256, 0, stream>>>((const int*)src, (const int*)dst,
                                    (const unsigned short*)feat,
                                    (const unsigned short*)W, flags);
    k_count<<<NCH, 256, 0, stream>>>(dst, cnt, flags);
    k_scan2<<<NB, 256, 0, stream>>>(cnt, loff, binsum);
    k_scanbin<<<1, 256, 0, stream>>>(binsum, binoff, rowptr);
    k_stage<<<NCH, 256, 0, stream>>>(src, dst, binoff, loff, staged, flags);
    k_fill<<<NB, 512, 0, stream>>>(staged, binoff, rowptr, norm, srclist);
    k_prescale<<<(NN * DD / 4 + 255) / 256, 256, 0, stream>>>(feat, norm, X1, flags);
    k_gather<<<(NN + 3) / 4, 256, 0, stream>>>(X1, rowptr, srclist, norm, X2, 0);
    k_gather<<<(NN + 3) / 4, 256, 0, stream>>>(X2, rowptr, srclist, norm, X1, 1);
    k_gemm2<<<(NN + 63) / 64, 256, 0, stream>>>(X1, W, b, d_out, flags);
}